// Round 1
// baseline (1449.312 us; speedup 1.0000x reference)
//
#include <hip/hip_runtime.h>
#include <hip/hip_bf16.h>

// Problem constants
#define FH 96
#define FW 96
#define NPOS (FH*FW)          // 9216
#define C 512
#define NA 9
#define NANCH (NPOS*NA)       // 82944
#define NPAD 131072           // 2^17 for bitonic
#define MAXOUT 1000
#define NMS_T 0.1f

// ---------------- Conv 3x3 (implicit GEMM, fp32 VALU) ----------------
// out[p][co] = relu( sum_{t,ci} feat[y+dy][x+dx][ci] * Wr[(t*512+ci)*512+co] + br[co] )
#define BM 64
#define BN 64
#define BK 32

__launch_bounds__(256)
__global__ void conv3x3_kernel(const float* __restrict__ feat,
                               const float* __restrict__ Wr,
                               const float* __restrict__ br,
                               float* __restrict__ xout) {
  __shared__ float As[BK][BM];
  __shared__ float Bs[BK][BN];
  const int tid = threadIdx.x;
  const int bm = blockIdx.y * BM;   // spatial base
  const int bn = blockIdx.x * BN;   // out-channel base

  // A staging: thread -> (pos_local = tid>>2, aq = tid&3) loads 8 ci
  const int apos = tid >> 2, aq = tid & 3;
  const int p = bm + apos;
  const int py = p / FW, px = p % FW;
  // B staging: thread -> (bk = tid>>3 row, (tid&7)*8 cols)
  const int bkr = tid >> 3, bn8 = (tid & 7) * 8;
  // micro tile 4x4: rows mr.., cols nr..
  const int mr = (tid >> 4) * 4, nr = (tid & 15) * 4;

  float acc[4][4] = {};

  for (int kb = 0; kb < 144; ++kb) {
    const int t = kb >> 4;              // tap 0..8
    const int ci0 = (kb & 15) * 32;     // ci base for this step
    const int dy = t / 3 - 1, dx = t % 3 - 1;
    const int yy = py + dy, xx = px + dx;
    float4 va0 = make_float4(0.f,0.f,0.f,0.f);
    float4 va1 = make_float4(0.f,0.f,0.f,0.f);
    if ((unsigned)yy < (unsigned)FH && (unsigned)xx < (unsigned)FW) {
      const float* src = feat + ((size_t)(yy * FW + xx) * C + ci0 + aq * 8);
      va0 = *(const float4*)src;
      va1 = *(const float4*)(src + 4);
    }
    const float* wsrc = Wr + ((size_t)(kb * 32 + bkr) * C + bn + bn8);
    const float4 vb0 = *(const float4*)wsrc;
    const float4 vb1 = *(const float4*)(wsrc + 4);

    __syncthreads();   // previous iteration's LDS reads complete
    {
      const int ak = aq * 8;
      As[ak+0][apos] = va0.x; As[ak+1][apos] = va0.y;
      As[ak+2][apos] = va0.z; As[ak+3][apos] = va0.w;
      As[ak+4][apos] = va1.x; As[ak+5][apos] = va1.y;
      As[ak+6][apos] = va1.z; As[ak+7][apos] = va1.w;
      *(float4*)&Bs[bkr][bn8]     = vb0;
      *(float4*)&Bs[bkr][bn8 + 4] = vb1;
    }
    __syncthreads();

    #pragma unroll
    for (int kk = 0; kk < BK; ++kk) {
      const float4 av = *(const float4*)&As[kk][mr];
      const float4 bv = *(const float4*)&Bs[kk][nr];
      acc[0][0] += av.x*bv.x; acc[0][1] += av.x*bv.y; acc[0][2] += av.x*bv.z; acc[0][3] += av.x*bv.w;
      acc[1][0] += av.y*bv.x; acc[1][1] += av.y*bv.y; acc[1][2] += av.y*bv.z; acc[1][3] += av.y*bv.w;
      acc[2][0] += av.z*bv.x; acc[2][1] += av.z*bv.y; acc[2][2] += av.z*bv.z; acc[2][3] += av.z*bv.w;
      acc[3][0] += av.w*bv.x; acc[3][1] += av.w*bv.y; acc[3][2] += av.w*bv.z; acc[3][3] += av.w*bv.w;
    }
  }

  const float b0 = br[bn+nr], b1 = br[bn+nr+1], b2 = br[bn+nr+2], b3 = br[bn+nr+3];
  #pragma unroll
  for (int i = 0; i < 4; ++i) {
    const int pp = bm + mr + i;
    float4 o;
    o.x = fmaxf(acc[i][0] + b0, 0.f);
    o.y = fmaxf(acc[i][1] + b1, 0.f);
    o.z = fmaxf(acc[i][2] + b2, 0.f);
    o.w = fmaxf(acc[i][3] + b3, 0.f);
    *(float4*)(xout + (size_t)pp * C + bn + nr) = o;
  }
}

// ---------------- Head: 1x1 convs + sigmoid + bbox decode + sort keys ----------------
__launch_bounds__(256)
__global__ void head_kernel(const float* __restrict__ x,
                            const float* __restrict__ Wc, const float* __restrict__ bc,
                            const float* __restrict__ Wb, const float* __restrict__ bb,
                            const float* __restrict__ anchors, const int* __restrict__ im_size,
                            float* __restrict__ scores, float* __restrict__ props,
                            unsigned long long* __restrict__ keys) {
  const int a = blockIdx.x * 256 + threadIdx.x;
  if (a >= NANCH) { keys[a] = 0ull; return; }   // padding keys for bitonic
  const int pos = a / NA, j = a - pos * NA;
  const float* xr = x + (size_t)pos * C;
  float accn = bc[j], accp = bc[j + NA];
  float d0 = bb[4*j], d1 = bb[4*j+1], d2 = bb[4*j+2], d3 = bb[4*j+3];
  for (int k = 0; k < C; ++k) {
    const float xv = xr[k];
    accn += xv * Wc[k * 18 + j];
    accp += xv * Wc[k * 18 + j + NA];
    const float4 wb = *(const float4*)(Wb + (size_t)k * 36 + 4 * j);
    d0 += xv * wb.x; d1 += xv * wb.y; d2 += xv * wb.z; d3 += xv * wb.w;
  }
  const float score = 1.0f / (1.0f + expf(accn - accp));   // sigmoid(pos-neg)
  const float4 anc = *(const float4*)(anchors + (size_t)4 * a);
  const float w  = anc.z - anc.x + 1.0f;
  const float h  = anc.w - anc.y + 1.0f;
  const float cx = anc.x + 0.5f * w;
  const float cy = anc.y + 0.5f * h;
  const float pcx = d0 * w + cx;
  const float pcy = d1 * h + cy;
  const float pw  = expf(d2) * w;
  const float ph  = expf(d3) * h;
  const float lim = (float)(*im_size - 1);
  float x1 = fminf(fmaxf(pcx - 0.5f * pw, 0.f), lim);
  float y1 = fminf(fmaxf(pcy - 0.5f * ph, 0.f), lim);
  float x2 = fminf(fmaxf(pcx + 0.5f * pw, 0.f), lim);
  float y2 = fminf(fmaxf(pcy + 0.5f * ph, 0.f), lim);
  *(float4*)(props + (size_t)4 * a) = make_float4(x1, y1, x2, y2);
  scores[a] = score;
  // descending sort key: score bits (positive -> monotonic), tie-break lower index first
  keys[a] = ((unsigned long long)__float_as_uint(score) << 32) | (unsigned)(~(unsigned)a);
}

// ---------------- Bitonic sort (descending), 2^17 elements ----------------
__launch_bounds__(1024)
__global__ void bitonic_local(unsigned long long* __restrict__ keys) {
  __shared__ unsigned long long s[4096];
  const int tid = threadIdx.x;
  const unsigned base = blockIdx.x * 4096u;
  for (int i = tid; i < 4096; i += 1024) s[i] = keys[base + i];
  __syncthreads();
  for (int k = 2; k <= 4096; k <<= 1) {
    for (int j = k >> 1; j > 0; j >>= 1) {
      for (int pr = tid; pr < 2048; pr += 1024) {
        const int i = ((pr / j) * 2 * j) + (pr % j);
        const int ixj = i + j;
        const bool descFirst = (((base + i) & (unsigned)k) == 0u);
        const unsigned long long av = s[i], bv = s[ixj];
        if (descFirst ? (av < bv) : (av > bv)) { s[i] = bv; s[ixj] = av; }
      }
      __syncthreads();
    }
  }
  for (int i = tid; i < 4096; i += 1024) keys[base + i] = s[i];
}

__launch_bounds__(256)
__global__ void bitonic_global(unsigned long long* __restrict__ keys, int k, int j) {
  const int pr = blockIdx.x * 256 + threadIdx.x;   // < 65536
  const int i = (pr / j) * 2 * j + (pr % j);
  const int ixj = i + j;
  const bool descFirst = ((i & k) == 0);
  const unsigned long long av = keys[i], bv = keys[ixj];
  if (descFirst ? (av < bv) : (av > bv)) { keys[i] = bv; keys[ixj] = av; }
}

__launch_bounds__(1024)
__global__ void bitonic_merge(unsigned long long* __restrict__ keys, int k) {
  __shared__ unsigned long long s[4096];
  const int tid = threadIdx.x;
  const unsigned base = blockIdx.x * 4096u;
  for (int i = tid; i < 4096; i += 1024) s[i] = keys[base + i];
  __syncthreads();
  const bool descFirst = ((base & (unsigned)k) == 0u);  // uniform: k >= 8192
  for (int j = 2048; j > 0; j >>= 1) {
    for (int pr = tid; pr < 2048; pr += 1024) {
      const int i = ((pr / j) * 2 * j) + (pr % j);
      const int ixj = i + j;
      const unsigned long long av = s[i], bv = s[ixj];
      if (descFirst ? (av < bv) : (av > bv)) { s[i] = bv; s[ixj] = av; }
    }
    __syncthreads();
  }
  for (int i = tid; i < 4096; i += 1024) keys[base + i] = s[i];
}

// ---------------- NMS: sorted greedy walk with LDS spatial hash ----------------
#define NCELL 48
#define CCAP 8

__launch_bounds__(1024)
__global__ void nms_kernel(const unsigned long long* __restrict__ keys,
                           const float* __restrict__ props,
                           int* __restrict__ kept_idx,
                           int* __restrict__ kept_count) {
  __shared__ float kx1[MAXOUT], ky1[MAXOUT], kx2[MAXOUT], ky2[MAXOUT], kar[MAXOUT];
  __shared__ unsigned short cellent[NCELL * NCELL * CCAP];
  __shared__ unsigned char cellcnt[NCELL * NCELL];
  __shared__ int s_kept, s_done;
  const int tid = threadIdx.x;
  for (int i = tid; i < NCELL * NCELL; i += 1024) cellcnt[i] = 0;
  if (tid == 0) { s_kept = 0; s_done = 0; }
  __syncthreads();
  const int mywave = tid >> 6, lane = tid & 63;

  for (int chunk = 0; chunk < NPAD / 1024; ++chunk) {
    if (s_done) break;   // uniform (post-barrier)
    const int ci = (chunk << 10) + tid;
    const unsigned long long key = keys[ci];
    const bool valid = (key >> 32) != 0ull;
    const int idx = (int)(~(unsigned)(key & 0xFFFFFFFFull));
    float x1 = 0.f, y1 = 0.f, x2 = 0.f, y2 = 0.f, ar = 0.f;
    if (valid) {
      const float4 b = *(const float4*)(props + ((size_t)idx << 2));
      x1 = b.x; y1 = b.y; x2 = b.z; y2 = b.w;
      ar = (x2 - x1) * (y2 - y1);
    }
    for (int sub = 0; sub < 16; ++sub) {
      if (mywave == sub && !s_done) {
        const int kcStart = s_kept;
        bool alive = valid;
        // ---- check against kept boxes via cell hash (exact; fallback on overflow)
        if (alive) {
          const int gx0 = (int)(x1 * 0.03125f), gxe = (int)(x2 * 0.03125f);
          const int gy0 = (int)(y1 * 0.03125f), gye = (int)(y2 * 0.03125f);
          bool fb = false;
          for (int gy = gy0; gy <= gye && alive && !fb; ++gy) {
            for (int gx = gx0; gx <= gxe && alive && !fb; ++gx) {
              const int cell = gy * NCELL + gx;
              const int cnt = cellcnt[cell];
              if (cnt > CCAP) { fb = true; break; }
              for (int e = 0; e < cnt; ++e) {
                const int kk = cellent[cell * CCAP + e];
                const float ix1 = fmaxf(x1, kx1[kk]), iy1 = fmaxf(y1, ky1[kk]);
                const float ix2 = fminf(x2, kx2[kk]), iy2 = fminf(y2, ky2[kk]);
                const float inter = fmaxf(ix2 - ix1, 0.f) * fmaxf(iy2 - iy1, 0.f);
                const float iou = inter / (ar + kar[kk] - inter + 1e-8f);
                if (iou > NMS_T) { alive = false; break; }
              }
            }
          }
          if (fb && alive) {
            for (int kk = 0; kk < kcStart && alive; ++kk) {
              const float ix1 = fmaxf(x1, kx1[kk]), iy1 = fmaxf(y1, ky1[kk]);
              const float ix2 = fminf(x2, kx2[kk]), iy2 = fminf(y2, ky2[kk]);
              const float inter = fmaxf(ix2 - ix1, 0.f) * fmaxf(iy2 - iy1, 0.f);
              const float iou = inter / (ar + kar[kk] - inter + 1e-8f);
              if (iou > NMS_T) alive = false;
            }
          }
        }
        // ---- intra-wave greedy resolution (sorted order = lane order)
        int kc = kcStart;
        while (true) {
          const unsigned long long ball = __ballot(alive);
          if (ball == 0ull || kc >= MAXOUT) break;
          const int src = __ffsll(ball) - 1;
          const float bx1 = __shfl(x1, src), by1 = __shfl(y1, src);
          const float bx2 = __shfl(x2, src), by2 = __shfl(y2, src);
          const float bar = __shfl(ar, src);
          if (lane == src) {
            kx1[kc] = x1; ky1[kc] = y1; kx2[kc] = x2; ky2[kc] = y2; kar[kc] = ar;
            kept_idx[kc] = idx;
            const int gx0 = (int)(x1 * 0.03125f), gxe = (int)(x2 * 0.03125f);
            const int gy0 = (int)(y1 * 0.03125f), gye = (int)(y2 * 0.03125f);
            for (int gy = gy0; gy <= gye; ++gy)
              for (int gx = gx0; gx <= gxe; ++gx) {
                const int cell = gy * NCELL + gx;
                const int cnt = cellcnt[cell];
                if (cnt < CCAP) {
                  cellent[cell * CCAP + cnt] = (unsigned short)kc;
                  cellcnt[cell] = (unsigned char)(cnt + 1);
                } else {
                  cellcnt[cell] = (unsigned char)(CCAP + 1);  // overflow marker
                }
              }
            alive = false;
          }
          if (alive) {
            const float ix1 = fmaxf(x1, bx1), iy1 = fmaxf(y1, by1);
            const float ix2 = fminf(x2, bx2), iy2 = fminf(y2, by2);
            const float inter = fmaxf(ix2 - ix1, 0.f) * fmaxf(iy2 - iy1, 0.f);
            const float iou = inter / (ar + bar - inter + 1e-8f);
            if (iou > NMS_T) alive = false;
          }
          kc++;
        }
        if (lane == 0) { s_kept = kc; if (kc >= MAXOUT) s_done = 1; }
      }
      __syncthreads();
    }
  }
  if (tid == 0) *kept_count = s_kept;
}

// ---------------- Output assembly ----------------
__launch_bounds__(256)
__global__ void output_kernel(const int* __restrict__ kept_idx, const int* __restrict__ kept_count,
                              const float* __restrict__ props, const float* __restrict__ scores,
                              float* __restrict__ out) {
  const int k = blockIdx.x * 256 + threadIdx.x;
  if (k >= MAXOUT) return;
  const int kc = *kept_count;
  if (k < kc) {
    const int idx = kept_idx[k];
    const float4 b = *(const float4*)(props + ((size_t)idx << 2));
    out[k * 5 + 0] = 0.f;
    out[k * 5 + 1] = b.x;
    out[k * 5 + 2] = b.y;
    out[k * 5 + 3] = b.z;
    out[k * 5 + 4] = b.w;
    out[5 * MAXOUT + k] = scores[idx];
  } else {
    out[k * 5 + 0] = 0.f;
    out[k * 5 + 1] = -1.f;
    out[k * 5 + 2] = -1.f;
    out[k * 5 + 3] = -1.f;
    out[k * 5 + 4] = -1.f;
    out[5 * MAXOUT + k] = -1.f;
  }
}

extern "C" void kernel_launch(void* const* d_in, const int* in_sizes, int n_in,
                              void* d_out, int out_size, void* d_ws, size_t ws_size,
                              hipStream_t stream) {
  const float* feat    = (const float*)d_in[0];
  const float* anchors = (const float*)d_in[1];
  const float* Wr      = (const float*)d_in[2];
  const float* br      = (const float*)d_in[3];
  const float* Wc      = (const float*)d_in[4];
  const float* bc      = (const float*)d_in[5];
  const float* Wb      = (const float*)d_in[6];
  const float* bb      = (const float*)d_in[7];
  const int*   im      = (const int*)d_in[8];
  float* out = (float*)d_out;

  char* ws = (char*)d_ws;
  // workspace layout (all 256B-aligned); total ~21.6 MB
  float* x                  = (float*)(ws);                       // 9216*512*4      = 18,874,368
  float* scores             = (float*)(ws + 18874368);            // 82944*4         =    331,776
  float* props              = (float*)(ws + 19206144);            // 82944*4*4       =  1,327,104
  unsigned long long* keys  = (unsigned long long*)(ws + 20533248); // 131072*8      =  1,048,576
  int* kept_idx             = (int*)(ws + 21581824);              // 1000*4 (pad 4K)
  int* kept_cnt             = (int*)(ws + 21585920);              // 4

  conv3x3_kernel<<<dim3(8, 144), 256, 0, stream>>>(feat, Wr, br, x);
  head_kernel<<<512, 256, 0, stream>>>(x, Wc, bc, Wb, bb, anchors, im, scores, props, keys);

  bitonic_local<<<32, 1024, 0, stream>>>(keys);
  for (int k = 8192; k <= 131072; k <<= 1) {
    for (int j = k >> 1; j >= 4096; j >>= 1)
      bitonic_global<<<256, 256, 0, stream>>>(keys, k, j);
    bitonic_merge<<<32, 1024, 0, stream>>>(keys, k);
  }

  nms_kernel<<<1, 1024, 0, stream>>>(keys, props, kept_idx, kept_cnt);
  output_kernel<<<4, 256, 0, stream>>>(kept_idx, kept_cnt, props, scores, out);
}